// Round 2
// baseline (1699.297 us; speedup 1.0000x reference)
//
#include <hip/hip_runtime.h>
#include <hip/hip_fp16.h>
#include <math.h>

#define SD 10
#define BB 7                  // bucket bits (nodes-per-bucket = 128)
#define BSZ 128               // nodes per bucket
#define MAXNB 2048            // LDS hist capacity; N <= 2048*128 = 262144
#define EB 512                // edge-chunk blocks (must be 512: round kernel assumes 2/thread)
#define CTHR 1024             // threads for count/scatter

typedef unsigned uvec4 __attribute__((ext_vector_type(4)));
union U32H2 { unsigned u; __half2 h; };

__device__ __forceinline__ float tanh_fast(float x) {
    float e = __expf(2.0f * x);
    float r = __builtin_amdgcn_rcpf(1.0f + e);
    return 1.0f - 2.0f * r;
}

__device__ __forceinline__ float softplus_f(float x) {
    return fmaxf(x, 0.0f) + log1pf(expf(-fabsf(x)));
}

// ===================== prep =====================

__global__ __launch_bounds__(256) void coords4_kernel(
    const float* __restrict__ coords, float4* __restrict__ coords4, int N)
{
    int n = blockIdx.x * blockDim.x + threadIdx.x;
    if (n >= N) return;
    float4 c;
    c.x = coords[n * 3 + 0];
    c.y = coords[n * 3 + 1];
    c.z = coords[n * 3 + 2];
    c.w = 0.0f;
    coords4[n] = c;
}

// ===================== build =====================

// Pass A: per-(bucket, block) counts. gcnt[k*EB + b].
__global__ __launch_bounds__(CTHR) void bucket_count_kernel(
    const int* __restrict__ nto, unsigned* __restrict__ gcnt, int E, int NB)
{
    __shared__ unsigned h[MAXNB];
    int b = blockIdx.x;
    for (int i = threadIdx.x; i < NB; i += CTHR) h[i] = 0;
    __syncthreads();
    long long ebeg = (long long)E * b / EB;
    long long eend = (long long)E * (b + 1) / EB;
    for (long long e = ebeg + threadIdx.x; e < eend; e += CTHR)
        atomicAdd(&h[((unsigned)nto[e]) >> BB], 1u);
    __syncthreads();
    for (int k = threadIdx.x; k < NB; k += CTHR) gcnt[(size_t)k * EB + b] = h[k];
}

// Pass B: block-major emit. Block b writes its chunk [ebeg,eend) CONTIGUOUSLY,
// locally ordered by bucket (offsets from an in-block scan of its gcnt column).
// All payload stores land in a block-private ~200KB region -> full-line combining
// in the block's own XCD L2, no cross-XCD partial-line sharing (the 2x write-amp
// + store-stall fix). Also emits eaddr[k][b] = absolute start of segment (k,b).
__global__ __launch_bounds__(CTHR) void bucket_scatter_kernel(
    const float4* __restrict__ coords4,
    const float* __restrict__ elen,
    const float* __restrict__ evec,
    const int* __restrict__ nfrom,
    const int* __restrict__ nto,
    const unsigned* __restrict__ gcnt,
    unsigned* __restrict__ eaddr,
    uvec4* __restrict__ payload,
    int E, int NB)
{
    __shared__ unsigned cur[MAXNB];       // 8 KB
    __shared__ unsigned scn[CTHR];        // 4 KB
    int b = blockIdx.x;
    int t = threadIdx.x;
    long long ebeg = (long long)E * b / EB;
    long long eend = (long long)E * (b + 1) / EB;

    // column-b counts for pair (2t, 2t+1); NB <= 2048 guaranteed by launcher
    unsigned a0 = (2 * t < NB) ? gcnt[(size_t)(2 * t) * EB + b] : 0u;
    unsigned a1 = (2 * t + 1 < NB) ? gcnt[(size_t)(2 * t + 1) * EB + b] : 0u;
    scn[t] = a0 + a1;
    __syncthreads();
    for (int d = 1; d < CTHR; d <<= 1) {
        unsigned x = (t >= d) ? scn[t - d] : 0u;
        __syncthreads();
        scn[t] += x;
        __syncthreads();
    }
    unsigned excl = t ? scn[t - 1] : 0u;
    unsigned s0 = (unsigned)ebeg + excl;
    unsigned s1 = s0 + a0;
    if (2 * t < NB)     { cur[2 * t] = s0;     eaddr[(size_t)(2 * t) * EB + b] = s0; }
    if (2 * t + 1 < NB) { cur[2 * t + 1] = s1; eaddr[(size_t)(2 * t + 1) * EB + b] = s1; }
    __syncthreads();

    for (long long e = ebeg + t; e < eend; e += CTHR) {
        int nf = nfrom[e];
        int nt = nto[e];
        unsigned k = ((unsigned)nt) >> BB;
        unsigned pos = atomicAdd(&cur[k], 1u);

        float4 cf = coords4[nf];
        float4 ct = coords4[nt];
        float ev0 = evec[e * 3 + 0], ev1 = evec[e * 3 + 1], ev2 = evec[e * 3 + 2];

        float g0 = elen[e];
        float g1 = fabsf(cf.x) + fabsf(cf.y) + fabsf(cf.z);
        float g2 = cf.x * ct.x + cf.y * ct.y + cf.z * ct.z;
        float g3 = cf.x * ev0 + cf.y * ev1 + cf.z * ev2;

        U32H2 c01, c23;
        c01.h = __floats2half2_rn(g0, g1);
        c23.h = __floats2half2_rn(g2, g3);
        uvec4 p;
        p.x = (unsigned)nf | (((unsigned)nt & (BSZ - 1)) << 18);
        p.y = c01.u;
        p.z = c23.u;
        p.w = 0u;
        payload[pos] = p;
    }
}

// ===================== rounds =====================

// wsth[n][j] = fp16( bm[j] + sum_k state[n][k] * Wm[k][j] ), dense 20B rows (4MB total)
__global__ __launch_bounds__(256) void wstate_kernel(
    const float* __restrict__ state, const float* __restrict__ Wm,
    const float* __restrict__ bm, __half* __restrict__ wsth, int N)
{
    int n = blockIdx.x * blockDim.x + threadIdx.x;
    if (n >= N) return;
    const float2* sp = (const float2*)(state + (size_t)n * SD);
    float s[SD];
#pragma unroll
    for (int h = 0; h < 5; h++) { float2 v = sp[h]; s[2*h] = v.x; s[2*h+1] = v.y; }
    float t[SD];
#pragma unroll
    for (int j = 0; j < SD; j++) t[j] = bm[j];
#pragma unroll
    for (int k = 0; k < SD; k++) {
#pragma unroll
        for (int j = 0; j < SD; j++) t[j] += s[k] * Wm[k * SD + j];
    }
    unsigned* dp = (unsigned*)(wsth + (size_t)n * SD);   // 20B rows, 4B aligned
#pragma unroll
    for (int h = 0; h < 5; h++) {
        U32H2 cv;
        cv.h = __floats2half2_rn(t[2*h], t[2*h+1]);
        dp[h] = cv.u;
    }
}

// Gathering round kernel: block = bucket k (BSZ=128 nodes). Loads its gcnt/eaddr
// rows (coalesced), LDS-scans the 512 segment lengths -> opref, then 10 lanes/edge,
// 6 edges/wave-step over bucket-local indices; a monotone segment-walker (amortized
// <1 LDS probe per step) translates local index -> payload address. Payload is
// LLC-resident (just written, 102MB < 256MB). Per-edge LDS atomicAdd into acc.
template <bool FIRST>
__global__ __launch_bounds__(256) void round_gather_kernel(
    const unsigned* __restrict__ gcnt,
    const unsigned* __restrict__ eaddr,
    const uvec4* __restrict__ payload,
    const float* __restrict__ Wm,
    const float* __restrict__ bm,
    const __half* __restrict__ wsth,      // (N,10) dense fp16, incl bias
    const float* __restrict__ state_prev,
    float* __restrict__ state_next,
    int N)
{
    __shared__ float acc[BSZ * SD];       // 5.12 KB
    __shared__ unsigned opref[EB + 1];    // 2.05 KB
    __shared__ unsigned segst[EB];        // 2.05 KB
    __shared__ unsigned scn[256];
    int k = blockIdx.x;
    int t = threadIdx.x;
    for (int i = t; i < BSZ * SD; i += 256) acc[i] = 0.0f;

    // row k of gcnt/eaddr: 2 entries per thread (EB == 512, 256 threads)
    unsigned c0 = gcnt[(size_t)k * EB + 2 * t];
    unsigned c1 = gcnt[(size_t)k * EB + 2 * t + 1];
    segst[2 * t]     = eaddr[(size_t)k * EB + 2 * t];
    segst[2 * t + 1] = eaddr[(size_t)k * EB + 2 * t + 1];
    scn[t] = c0 + c1;
    __syncthreads();
    for (int d = 1; d < 256; d <<= 1) {
        unsigned x = (t >= d) ? scn[t - d] : 0u;
        __syncthreads();
        scn[t] += x;
        __syncthreads();
    }
    unsigned excl = t ? scn[t - 1] : 0u;
    opref[2 * t] = excl;
    opref[2 * t + 1] = excl + c0;
    if (t == 255) opref[EB] = excl + c0 + c1;
    __syncthreads();
    unsigned len = opref[EB];

    int lane = threadIdx.x & 63;
    int wv = threadIdx.x >> 6;            // 0..3
    int grp0 = lane / 10;
    bool active = grp0 < 6;
    int grp = active ? grp0 : 5;
    int j = active ? (lane - grp0 * 10) : (lane - 60);

    float w0 = Wm[10 * SD + j];
    float w1 = Wm[11 * SD + j];
    float w2 = Wm[12 * SD + j];
    float w3 = Wm[13 * SD + j];
    float bb = bm[j];

    if (len) {
        unsigned Q = (len + 3) >> 2;
        unsigned rbeg = (unsigned)wv * Q;
        unsigned rend = rbeg + Q; if (rend > len) rend = len;
        unsigned lm1 = len - 1;

        // preload: payload depth 2, wst depth 1; monotone walker bw
        unsigned i0 = rbeg + (unsigned)grp;
        unsigned i0c = i0 < len ? i0 : lm1;
        unsigned blo = 0, bhi = EB;
#pragma unroll
        for (int s = 0; s < 9; s++) {
            unsigned mid = (blo + bhi) >> 1;
            if (opref[mid] <= i0c) blo = mid; else bhi = mid;
        }
        unsigned bw = blo;
        uvec4 P0 = payload[segst[bw] + (i0c - opref[bw])];
        unsigned i1c = i0 + 6; if (i1c > lm1) i1c = lm1;
        while (opref[bw + 1] <= i1c) bw++;
        uvec4 P1 = payload[segst[bw] + (i1c - opref[bw])];
        float T0 = bb, T1 = bb;
        if (!FIRST) T0 = __half2float(wsth[(size_t)(P0.x & 0x3FFFFu) * SD + j]);

        for (unsigned base = rbeg; base < rend; base += 6) {
            unsigned i2 = base + 12 + (unsigned)grp;
            unsigned i2c = i2 > lm1 ? lm1 : i2;
            while (opref[bw + 1] <= i2c) bw++;
            uvec4 P2 = payload[segst[bw] + (i2c - opref[bw])];
            if (!FIRST) T1 = __half2float(wsth[(size_t)(P1.x & 0x3FFFFu) * SD + j]);
            unsigned i = base + (unsigned)grp;
            if (active && i < rend) {
                int lnt = (int)((P0.x >> 18) & (BSZ - 1));
                U32H2 c01, c23;
                c01.u = P0.y; c23.u = P0.z;
                float g0 = __low2float(c01.h), g1 = __high2float(c01.h);
                float g2 = __low2float(c23.h), g3 = __high2float(c23.h);
                float tt = T0 + g0 * w0 + g1 * w1 + g2 * w2 + g3 * w3;
                atomicAdd(&acc[lnt * SD + j], tanh_fast(tt));
            }
            P0 = P1; P1 = P2; T0 = T1;
        }
    }
    __syncthreads();

    int base_o = k * BSZ * SD;
    int lim = N * SD - base_o;
    for (int i = t; i < BSZ * SD; i += 256) {
        if (i < lim) {
            float v = acc[i];
            if (!FIRST) v += state_prev[base_o + i];
            state_next[base_o + i] = v;
        }
    }
}

// ===================== graph phase =====================

__global__ __launch_bounds__(256) void goff_kernel(
    const int* __restrict__ gidx, unsigned* __restrict__ goff, int N, int G)
{
    int n = blockIdx.x * blockDim.x + threadIdx.x;
    if (n >= N) return;
    int g = gidx[n];
    if (n == 0) {
        for (int q = 0; q <= g; q++) goff[q] = 0;
    } else {
        int gp = gidx[n - 1];
        for (int q = gp + 1; q <= g; q++) goff[q] = (unsigned)n;
    }
    if (n == N - 1) {
        for (int q = g + 1; q <= G; q++) goff[q] = (unsigned)N;
    }
}

// 4-way split per (g,j); one atomic per partial. gstate must be zeroed.
__global__ __launch_bounds__(256) void gsum_kernel(
    const float* __restrict__ state, const unsigned* __restrict__ goff,
    float* __restrict__ gstate, int G)
{
    int tid = blockIdx.x * blockDim.x + threadIdx.x;
    if (tid >= G * SD * 4) return;
    int s = tid & 3;
    int rest = tid >> 2;
    int g = rest / SD;
    int j = rest - g * SD;
    unsigned beg = goff[g], end = goff[g + 1];
    unsigned len = end - beg;
    unsigned b0 = beg + (len * (unsigned)s) / 4u;
    unsigned b1 = beg + (len * (unsigned)(s + 1)) / 4u;
    float a = 0.0f;
    for (unsigned n = b0; n < b1; n++) a += state[(size_t)n * SD + j];
    atomicAdd(&gstate[(size_t)g * SD + j], a);
}

__global__ __launch_bounds__(256) void out_kernel(
    const float* __restrict__ gstate, const float* __restrict__ Wo,
    const float* __restrict__ bo, float* __restrict__ out, int G)
{
    int g = blockIdx.x * blockDim.x + threadIdx.x;
    if (g >= G) return;
    float s[SD];
#pragma unroll
    for (int k = 0; k < SD; k++) s[k] = gstate[(size_t)g * SD + k];
    float ev[4];
#pragma unroll
    for (int c = 0; c < 4; c++) {
        float a = bo[c];
#pragma unroll
        for (int k = 0; k < SD; k++) a += s[k] * Wo[k * 4 + c];
        ev[c] = a;
    }
    out[g * 4 + 0] = ev[0];
    out[g * 4 + 1] = softplus_f(ev[1]);
    out[g * 4 + 2] = softplus_f(ev[2]) + 1.0f;
    out[g * 4 + 3] = softplus_f(ev[3]);
}

// ===================== fallback (atomic path) =====================

template <bool FIRST>
__global__ __launch_bounds__(256) void edge_kernel_fb(
    const float* __restrict__ coords, const float* __restrict__ elen,
    const float* __restrict__ evec, const float* __restrict__ Wm,
    const float* __restrict__ bm, const int* __restrict__ nfrom,
    const int* __restrict__ nto, const float* __restrict__ state_prev,
    float* __restrict__ state_next, int E)
{
    int e = blockIdx.x * blockDim.x + threadIdx.x;
    if (e >= E) return;
    int nf = nfrom[e];
    int nt = nto[e];
    float cf0 = coords[nf*3+0], cf1 = coords[nf*3+1], cf2 = coords[nf*3+2];
    float ct0 = coords[nt*3+0], ct1 = coords[nt*3+1], ct2 = coords[nt*3+2];
    float ev0 = evec[e*3+0], ev1 = evec[e*3+1], ev2 = evec[e*3+2];
    float g0 = elen[e];
    float g1 = fabsf(cf0) + fabsf(cf1) + fabsf(cf2);
    float g2 = cf0*ct0 + cf1*ct1 + cf2*ct2;
    float g3 = cf0*ev0 + cf1*ev1 + cf2*ev2;
    float acc[SD];
#pragma unroll
    for (int j = 0; j < SD; j++) {
        acc[j] = bm[j] + g0*Wm[10*SD+j] + g1*Wm[11*SD+j] + g2*Wm[12*SD+j] + g3*Wm[13*SD+j];
    }
    if (!FIRST) {
        const float2* sp = (const float2*)(state_prev + (size_t)nf * SD);
        float s[SD];
#pragma unroll
        for (int h = 0; h < 5; h++) { float2 v = sp[h]; s[2*h] = v.x; s[2*h+1] = v.y; }
#pragma unroll
        for (int k = 0; k < SD; k++) {
#pragma unroll
            for (int j = 0; j < SD; j++) acc[j] += s[k] * Wm[k*SD+j];
        }
    }
    float* dst = state_next + (size_t)nt * SD;
#pragma unroll
    for (int j = 0; j < SD; j++) atomicAdd(dst + j, tanh_fast(acc[j]));
}

__global__ __launch_bounds__(256) void graph_reduce_fb(
    const float* __restrict__ state, const int* __restrict__ gidx,
    float* __restrict__ gstate, int N)
{
    int n = blockIdx.x * blockDim.x + threadIdx.x;
    if (n >= N) return;
    int g = gidx[n];
    const float2* sp = (const float2*)(state + (size_t)n * SD);
    float* dst = gstate + (size_t)g * SD;
#pragma unroll
    for (int h = 0; h < 5; h++) {
        float2 v = sp[h];
        atomicAdd(dst + 2*h, v.x);
        atomicAdd(dst + 2*h + 1, v.y);
    }
}

// ===================== launch =====================

extern "C" void kernel_launch(void* const* d_in, const int* in_sizes, int n_in,
                              void* d_out, int out_size, void* d_ws, size_t ws_size,
                              hipStream_t stream) {
    const float* coords = (const float*)d_in[0];
    const float* elen   = (const float*)d_in[1];
    const float* evec   = (const float*)d_in[2];
    const float* Wm     = (const float*)d_in[3];
    const float* bm     = (const float*)d_in[4];
    const float* Wo     = (const float*)d_in[5];
    const float* bo     = (const float*)d_in[6];
    const int* nfrom    = (const int*)d_in[7];
    const int* nto      = (const int*)d_in[8];
    const int* gidx     = (const int*)d_in[9];

    const int E = in_sizes[1];
    const int N = in_sizes[9];
    const int G = out_size / 4;

    const int NB = (N + BSZ - 1) / BSZ;      // buckets
    const size_t M = (size_t)NB * EB;        // per-(bucket,block) table size

    const int BLK = 256;
    const int ng = (N + BLK - 1) / BLK;
    const int gg = (G + BLK - 1) / BLK;

    auto align256 = [](size_t x) { return (x + 255) & ~(size_t)255; };
    const size_t state_bytes = align256((size_t)N * SD * sizeof(float));
    const size_t wst_bytes   = align256((size_t)N * SD * sizeof(__half) + 256);
    const size_t pay_bytes   = align256((size_t)E * sizeof(uvec4));
    const size_t gcnt_bytes  = align256(M * sizeof(unsigned));
    const size_t goff_bytes  = align256((size_t)(G + 1) * sizeof(unsigned));
    const size_t gst_bytes   = align256((size_t)G * SD * sizeof(float));
    const size_t c4_bytes    = align256((size_t)N * sizeof(float4));

    size_t o = 0;
    char* w = (char*)d_ws;
    float* stateA    = (float*)(w + o);    o += state_bytes;
    float* stateB    = (float*)(w + o);    o += state_bytes;
    __half* wsth     = (__half*)(w + o);   o += wst_bytes;
    uvec4* payload   = (uvec4*)(w + o);    o += pay_bytes;
    unsigned* gcnt   = (unsigned*)(w + o); o += gcnt_bytes;
    unsigned* eaddr  = (unsigned*)(w + o); o += gcnt_bytes;
    unsigned* goff   = (unsigned*)(w + o); o += goff_bytes;
    float* gstate    = (float*)(w + o);    o += gst_bytes;
    float4* coords4  = (float4*)(w + o);   o += c4_bytes;

    if (o <= ws_size && NB <= MAXNB && N < (1 << 18)) {
        // ---- prep + build (no global scan, no global atomics) ----
        coords4_kernel<<<ng, BLK, 0, stream>>>(coords, coords4, N);
        bucket_count_kernel<<<EB, CTHR, 0, stream>>>(nto, gcnt, E, NB);
        bucket_scatter_kernel<<<EB, CTHR, 0, stream>>>(coords4, elen, evec, nfrom, nto,
                                                       gcnt, eaddr, payload, E, NB);
        // ---- rounds ----
        round_gather_kernel<true><<<NB, BLK, 0, stream>>>(gcnt, eaddr, payload, Wm, bm,
                                                          wsth, stateB, stateA, N);
        wstate_kernel<<<ng, BLK, 0, stream>>>(stateA, Wm, bm, wsth, N);
        round_gather_kernel<false><<<NB, BLK, 0, stream>>>(gcnt, eaddr, payload, Wm, bm,
                                                           wsth, stateA, stateB, N);
        wstate_kernel<<<ng, BLK, 0, stream>>>(stateB, Wm, bm, wsth, N);
        round_gather_kernel<false><<<NB, BLK, 0, stream>>>(gcnt, eaddr, payload, Wm, bm,
                                                           wsth, stateB, stateA, N);
        // ---- graph phase ----
        hipMemsetAsync(gstate, 0, (size_t)G * SD * sizeof(float), stream);
        goff_kernel<<<ng, BLK, 0, stream>>>(gidx, goff, N, G);
        gsum_kernel<<<(G * SD * 4 + BLK - 1) / BLK, BLK, 0, stream>>>(stateA, goff, gstate, G);
        out_kernel<<<gg, BLK, 0, stream>>>(gstate, Wo, bo, (float*)d_out, G);
    } else {
        // ---- fallback: atomic path ----
        const int eg = (E + BLK - 1) / BLK;
        float* gstateF = (float*)(w + 2 * state_bytes);
        hipMemsetAsync(stateA, 0, state_bytes, stream);
        hipMemsetAsync(gstateF, 0, (size_t)G * SD * sizeof(float), stream);
        edge_kernel_fb<true><<<eg, BLK, 0, stream>>>(coords, elen, evec, Wm, bm,
                                                     nfrom, nto, stateA, stateA, E);
        hipMemcpyAsync(stateB, stateA, state_bytes, hipMemcpyDeviceToDevice, stream);
        edge_kernel_fb<false><<<eg, BLK, 0, stream>>>(coords, elen, evec, Wm, bm,
                                                      nfrom, nto, stateA, stateB, E);
        hipMemcpyAsync(stateA, stateB, state_bytes, hipMemcpyDeviceToDevice, stream);
        edge_kernel_fb<false><<<eg, BLK, 0, stream>>>(coords, elen, evec, Wm, bm,
                                                      nfrom, nto, stateB, stateA, E);
        graph_reduce_fb<<<ng, BLK, 0, stream>>>(stateA, gidx, gstateF, N);
        out_kernel<<<gg, BLK, 0, stream>>>(gstateF, Wo, bo, (float*)d_out, G);
    }
}

// Round 4
// 894.768 us; speedup vs baseline: 1.8991x; 1.8991x over previous
//
#include <hip/hip_runtime.h>
#include <hip/hip_fp16.h>
#include <math.h>

#define SD 10
#define BB 8                  // bucket bits (nodes-per-bucket = 256)
#define BSZ 256               // nodes per bucket
#define MAXNB 1024            // N <= 1024*256 = 262144 (and N < 2^18 gate)
#define EB 512                // edge-chunk blocks (scatter/count grid)
#define CTHR 1024             // threads for count/scatter/sortperm
#define SPT 10                // sortperm staged entries/thread (cap 10240/bucket; avg 8192)

typedef unsigned uvec4 __attribute__((ext_vector_type(4)));
union U32H2 { unsigned u; __half2 h; };

__device__ __forceinline__ float tanh_fast(float x) {
    float e = __expf(2.0f * x);
    float r = __builtin_amdgcn_rcpf(1.0f + e);
    return 1.0f - 2.0f * r;
}

__device__ __forceinline__ float softplus_f(float x) {
    return fmaxf(x, 0.0f) + log1pf(expf(-fabsf(x)));
}

// ===================== prep =====================

__global__ __launch_bounds__(256) void coords4_kernel(
    const float* __restrict__ coords, float4* __restrict__ coords4, int N)
{
    int n = blockIdx.x * blockDim.x + threadIdx.x;
    if (n >= N) return;
    float4 c;
    c.x = coords[n * 3 + 0];
    c.y = coords[n * 3 + 1];
    c.z = coords[n * 3 + 2];
    c.w = 0.0f;
    coords4[n] = c;
}

// ===================== build =====================

// Pass A: per-(bucket, block) counts. gcnt[k*EB + b].
__global__ __launch_bounds__(CTHR) void bucket_count_kernel(
    const int* __restrict__ nto, unsigned* __restrict__ gcnt, int E, int NB)
{
    __shared__ unsigned h[MAXNB];
    int b = blockIdx.x;
    for (int i = threadIdx.x; i < NB; i += CTHR) h[i] = 0;
    __syncthreads();
    long long ebeg = (long long)E * b / EB;
    long long eend = (long long)E * (b + 1) / EB;
    for (long long e = ebeg + threadIdx.x; e < eend; e += CTHR)
        atomicAdd(&h[((unsigned)nto[e]) >> BB], 1u);
    __syncthreads();
    for (int k = threadIdx.x; k < NB; k += CTHR) gcnt[(size_t)k * EB + b] = h[k];
}

// Pass B: block-major emit. Block b writes its chunk [ebeg,eend) CONTIGUOUSLY,
// locally ordered by bucket. All stores land in a block-private ~400KB region ->
// full-line write combining, no cross-XCD partial-line sharing, no write-amp.
// Emits eaddr[k][b] = absolute start (block-major space) of segment (k,b).
__global__ __launch_bounds__(CTHR) void bucket_scatter_kernel(
    const float4* __restrict__ coords4,
    const float* __restrict__ elen,
    const float* __restrict__ evec,
    const int* __restrict__ nfrom,
    const int* __restrict__ nto,
    const unsigned* __restrict__ gcnt,
    unsigned* __restrict__ eaddr,
    uvec4* __restrict__ payload,
    int E, int NB)
{
    __shared__ unsigned cur[MAXNB];       // 4 KB
    __shared__ unsigned scn[CTHR];        // 4 KB
    int b = blockIdx.x;
    int t = threadIdx.x;
    long long ebeg = (long long)E * b / EB;
    long long eend = (long long)E * (b + 1) / EB;

    unsigned a0 = (t < NB) ? gcnt[(size_t)t * EB + b] : 0u;
    scn[t] = a0;
    __syncthreads();
    for (int d = 1; d < CTHR; d <<= 1) {
        unsigned x = (t >= d) ? scn[t - d] : 0u;
        __syncthreads();
        scn[t] += x;
        __syncthreads();
    }
    unsigned excl = t ? scn[t - 1] : 0u;
    if (t < NB) {
        unsigned s0 = (unsigned)ebeg + excl;
        cur[t] = s0;
        eaddr[(size_t)t * EB + b] = s0;
    }
    __syncthreads();

    for (long long e = ebeg + t; e < eend; e += CTHR) {
        int nf = nfrom[e];
        int nt = nto[e];
        unsigned k = ((unsigned)nt) >> BB;
        unsigned pos = atomicAdd(&cur[k], 1u);

        float4 cf = coords4[nf];
        float4 ct = coords4[nt];
        float ev0 = evec[e * 3 + 0], ev1 = evec[e * 3 + 1], ev2 = evec[e * 3 + 2];

        float g0 = elen[e];
        float g1 = fabsf(cf.x) + fabsf(cf.y) + fabsf(cf.z);
        float g2 = cf.x * ct.x + cf.y * ct.y + cf.z * ct.z;
        float g3 = cf.x * ev0 + cf.y * ev1 + cf.z * ev2;

        U32H2 c01, c23;
        c01.h = __floats2half2_rn(g0, g1);
        c23.h = __floats2half2_rn(g2, g3);
        uvec4 p;
        p.x = (unsigned)nf | (((unsigned)nt & (BSZ - 1)) << 18);
        p.y = c01.u;
        p.z = c23.u;
        p.w = 0u;
        payload[pos] = p;
    }
}

// Row sums of gcnt -> bsum[k] (bucket totals). EB == 512, 256 threads: 2 each.
__global__ __launch_bounds__(256) void rowsum_kernel(
    const unsigned* __restrict__ gcnt, unsigned* __restrict__ bsum)
{
    __shared__ unsigned red[256];
    int k = blockIdx.x, t = threadIdx.x;
    red[t] = gcnt[(size_t)k * EB + t] + gcnt[(size_t)k * EB + t + 256];
    __syncthreads();
    for (int d = 128; d > 0; d >>= 1) {
        if (t < d) red[t] += red[t + d];
        __syncthreads();
    }
    if (t == 0) bsum[k] = red[0];
}

// Exclusive scan of bsum (NB <= 1024) -> bstart[0..NB]. Single block.
__global__ __launch_bounds__(256) void bscan_kernel(
    const unsigned* __restrict__ bsum, unsigned* __restrict__ bstart, int NB, int E)
{
    __shared__ unsigned lds[256];
    int t = threadIdx.x;
    unsigned v[4], s = 0;
#pragma unroll
    for (int c = 0; c < 4; c++) {
        int i = t * 4 + c;
        v[c] = (i < NB) ? bsum[i] : 0u;
        s += v[c];
    }
    lds[t] = s;
    __syncthreads();
    for (int d = 1; d < 256; d <<= 1) {
        unsigned x = (t >= d) ? lds[t - d] : 0u;
        __syncthreads();
        lds[t] += x;
        __syncthreads();
    }
    unsigned run = t ? lds[t - 1] : 0u;
#pragma unroll
    for (int c = 0; c < 4; c++) {
        int i = t * 4 + c;
        if (i < NB) bstart[i] = run;
        run += v[c];
    }
    if (t == 255) bstart[NB] = (unsigned)E;
}

// Permute+sort (ONCE, not per round): per bucket k, gather its EB segments from the
// block-major buffer into registers (1024 threads x SPT independent loads -> high MLP,
// no serial walker), counting-sort by lnt, write the bucket CONTIGUOUSLY into dst.
// Rounds then stream dst with zero gather cost. Oversized buckets: unsorted copy
// (rounds handle arbitrary order correctly via run-accumulation).
__global__ __launch_bounds__(CTHR) void sortperm_kernel(
    const unsigned* __restrict__ gcnt,
    const unsigned* __restrict__ eaddr,
    const unsigned* __restrict__ bstart,
    const uvec4* __restrict__ src,
    uvec4* __restrict__ dst)
{
    __shared__ unsigned opref[EB + 1];    // 2.05 KB
    __shared__ unsigned segst[EB];        // 2 KB
    __shared__ unsigned hist[BSZ];        // 1 KB
    __shared__ unsigned scur[BSZ];        // 1 KB
    int k = blockIdx.x, t = threadIdx.x;

    unsigned cnt_t = 0;
    if (t < EB) {
        cnt_t = gcnt[(size_t)k * EB + t];
        segst[t] = eaddr[(size_t)k * EB + t];
        opref[t] = cnt_t;
    }
    if (t < BSZ) hist[t] = 0;
    __syncthreads();
    for (int d = 1; d < EB; d <<= 1) {           // Hillis-Steele inclusive scan
        unsigned x = 0;
        if (t < EB && t >= d) x = opref[t - d];
        __syncthreads();
        if (t < EB) opref[t] += x;
        __syncthreads();
    }
    unsigned incl = (t < EB) ? opref[t] : 0u;
    __syncthreads();
    if (t < EB) opref[t] = incl - cnt_t;         // exclusive
    if (t == EB - 1) opref[EB] = incl;
    __syncthreads();
    unsigned len = opref[EB];
    unsigned obase = bstart[k];

    if (len <= (unsigned)(CTHR * SPT)) {
        uvec4 st[SPT];
#pragma unroll
        for (int c = 0; c < SPT; c++) {
            unsigned i = (unsigned)t + (unsigned)c * CTHR;
            if (i < len) {
                unsigned lo = 0, hi = EB;
#pragma unroll
                for (int s = 0; s < 9; s++) {    // log2(EB)
                    unsigned mid = (lo + hi) >> 1;
                    if (opref[mid] <= i) lo = mid; else hi = mid;
                }
                st[c] = src[segst[lo] + (i - opref[lo])];
                atomicAdd(&hist[(st[c].x >> 18) & (BSZ - 1)], 1u);
            }
        }
        __syncthreads();
        if (t < BSZ) scur[t] = hist[t];
        __syncthreads();
        for (int d = 1; d < BSZ; d <<= 1) {
            unsigned x = 0;
            if (t < BSZ && t >= d) x = scur[t - d];
            __syncthreads();
            if (t < BSZ) scur[t] += x;
            __syncthreads();
        }
        if (t < BSZ) scur[t] = obase + scur[t] - hist[t];   // obase + exclusive
        __syncthreads();
#pragma unroll
        for (int c = 0; c < SPT; c++) {
            unsigned i = (unsigned)t + (unsigned)c * CTHR;
            if (i < len) {
                unsigned pos = atomicAdd(&scur[(st[c].x >> 18) & (BSZ - 1)], 1u);
                dst[pos] = st[c];
            }
        }
    } else {
        for (unsigned i = (unsigned)t; i < len; i += CTHR) {
            unsigned lo = 0, hi = EB;
#pragma unroll
            for (int s = 0; s < 9; s++) {
                unsigned mid = (lo + hi) >> 1;
                if (opref[mid] <= i) lo = mid; else hi = mid;
            }
            dst[obase + i] = src[segst[lo] + (i - opref[lo])];
        }
    }
}

// ===================== rounds =====================

// wsth[n][j] = fp16( bm[j] + sum_k state[n][k] * Wm[k][j] ), dense 20B rows (4MB total)
__global__ __launch_bounds__(256) void wstate_kernel(
    const float* __restrict__ state, const float* __restrict__ Wm,
    const float* __restrict__ bm, __half* __restrict__ wsth, int N)
{
    int n = blockIdx.x * blockDim.x + threadIdx.x;
    if (n >= N) return;
    const float2* sp = (const float2*)(state + (size_t)n * SD);
    float s[SD];
#pragma unroll
    for (int h = 0; h < 5; h++) { float2 v = sp[h]; s[2*h] = v.x; s[2*h+1] = v.y; }
    float t[SD];
#pragma unroll
    for (int j = 0; j < SD; j++) t[j] = bm[j];
#pragma unroll
    for (int k = 0; k < SD; k++) {
#pragma unroll
        for (int j = 0; j < SD; j++) t[j] += s[k] * Wm[k * SD + j];
    }
    unsigned* dp = (unsigned*)(wsth + (size_t)n * SD);   // 20B rows, 4B aligned
#pragma unroll
    for (int h = 0; h < 5; h++) {
        U32H2 cv;
        cv.h = __floats2half2_rn(t[2*h], t[2*h+1]);
        dp[h] = cv.u;
    }
}

// Run-accumulating round kernel: 10 lanes/edge, 6 edges/wave-step; each wave owns a
// CONTIGUOUS quarter of its bucket's (destination-sorted) edges, so a group's lnt is
// constant over runs -> accumulate tanh in a register, LDS-atomic only on run change.
// Payload is contiguous bucket-major (from sortperm) and LLC-resident.
template <bool FIRST>
__global__ __launch_bounds__(256) void round_run_kernel(
    const unsigned* __restrict__ bstart,
    const uvec4* __restrict__ payload,
    const float* __restrict__ Wm,
    const float* __restrict__ bm,
    const __half* __restrict__ wsth,      // (N,10) dense fp16, incl bias
    const float* __restrict__ state_prev,
    float* __restrict__ state_next,
    int N, int E)
{
    __shared__ float acc[BSZ * SD];       // 10 KB
    int k = blockIdx.x;
    for (int i = threadIdx.x; i < BSZ * SD; i += 256) acc[i] = 0.0f;

    int lane = threadIdx.x & 63;
    int wv = threadIdx.x >> 6;            // 0..3
    int grp0 = lane / 10;
    bool active = grp0 < 6;
    int grp = active ? grp0 : 5;
    int j = active ? (lane - grp0 * 10) : (lane - 60);

    float w0 = Wm[10 * SD + j];
    float w1 = Wm[11 * SD + j];
    float w2 = Wm[12 * SD + j];
    float w3 = Wm[13 * SD + j];
    float bb = bm[j];
    __syncthreads();

    unsigned beg = bstart[k], end = bstart[k + 1];
    unsigned len = end - beg;
    unsigned Q = (len + 3) >> 2;
    unsigned rbeg = beg + (unsigned)wv * Q;
    unsigned rend = rbeg + Q; if (rend > end) rend = end;
    unsigned eclamp = (unsigned)E - 1u;

    // pipeline preload: payload depth 2, wst depth 1
    unsigned e0 = rbeg + (unsigned)grp;
    uvec4 P0 = payload[e0 <= eclamp ? e0 : eclamp];
    unsigned e1 = e0 + 6;
    uvec4 P1 = payload[e1 <= eclamp ? e1 : eclamp];
    float T0 = bb, T1 = bb;
    if (!FIRST) T0 = __half2float(wsth[(size_t)(P0.x & 0x3FFFFu) * SD + j]);

    int cur_lnt = -1;
    float accv = 0.0f;

    for (unsigned base = rbeg; base < rend; base += 6) {
        unsigned e2 = base + 12 + (unsigned)grp;
        uvec4 P2 = payload[e2 <= eclamp ? e2 : eclamp];
        if (!FIRST) T1 = __half2float(wsth[(size_t)(P1.x & 0x3FFFFu) * SD + j]);
        unsigned e = base + (unsigned)grp;
        if (active && e < rend) {
            int lnt = (int)((P0.x >> 18) & (BSZ - 1));
            U32H2 c01, c23;
            c01.u = P0.y; c23.u = P0.z;
            float g0 = __low2float(c01.h), g1 = __high2float(c01.h);
            float g2 = __low2float(c23.h), g3 = __high2float(c23.h);
            float t = T0 + g0 * w0 + g1 * w1 + g2 * w2 + g3 * w3;
            if (lnt != cur_lnt) {
                if (cur_lnt >= 0) atomicAdd(&acc[cur_lnt * SD + j], accv);
                accv = 0.0f;
                cur_lnt = lnt;
            }
            accv += tanh_fast(t);
        }
        P0 = P1; P1 = P2; T0 = T1;
    }
    if (active && cur_lnt >= 0) atomicAdd(&acc[cur_lnt * SD + j], accv);
    __syncthreads();

    int base_o = k * BSZ * SD;
    int lim = N * SD - base_o;
    for (int i = threadIdx.x; i < BSZ * SD; i += 256) {
        if (i < lim) {
            float v = acc[i];
            if (!FIRST) v += state_prev[base_o + i];
            state_next[base_o + i] = v;
        }
    }
}

// ===================== graph phase =====================

__global__ __launch_bounds__(256) void goff_kernel(
    const int* __restrict__ gidx, unsigned* __restrict__ goff, int N, int G)
{
    int n = blockIdx.x * blockDim.x + threadIdx.x;
    if (n >= N) return;
    int g = gidx[n];
    if (n == 0) {
        for (int q = 0; q <= g; q++) goff[q] = 0;
    } else {
        int gp = gidx[n - 1];
        for (int q = gp + 1; q <= g; q++) goff[q] = (unsigned)n;
    }
    if (n == N - 1) {
        for (int q = g + 1; q <= G; q++) goff[q] = (unsigned)N;
    }
}

// 4-way split per (g,j); one atomic per partial. gstate must be zeroed.
__global__ __launch_bounds__(256) void gsum_kernel(
    const float* __restrict__ state, const unsigned* __restrict__ goff,
    float* __restrict__ gstate, int G)
{
    int tid = blockIdx.x * blockDim.x + threadIdx.x;
    if (tid >= G * SD * 4) return;
    int s = tid & 3;
    int rest = tid >> 2;
    int g = rest / SD;
    int j = rest - g * SD;
    unsigned beg = goff[g], end = goff[g + 1];
    unsigned len = end - beg;
    unsigned b0 = beg + (len * (unsigned)s) / 4u;
    unsigned b1 = beg + (len * (unsigned)(s + 1)) / 4u;
    float a = 0.0f;
    for (unsigned n = b0; n < b1; n++) a += state[(size_t)n * SD + j];
    atomicAdd(&gstate[(size_t)g * SD + j], a);
}

__global__ __launch_bounds__(256) void out_kernel(
    const float* __restrict__ gstate, const float* __restrict__ Wo,
    const float* __restrict__ bo, float* __restrict__ out, int G)
{
    int g = blockIdx.x * blockDim.x + threadIdx.x;
    if (g >= G) return;
    float s[SD];
#pragma unroll
    for (int k = 0; k < SD; k++) s[k] = gstate[(size_t)g * SD + k];
    float ev[4];
#pragma unroll
    for (int c = 0; c < 4; c++) {
        float a = bo[c];
#pragma unroll
        for (int k = 0; k < SD; k++) a += s[k] * Wo[k * 4 + c];
        ev[c] = a;
    }
    out[g * 4 + 0] = ev[0];
    out[g * 4 + 1] = softplus_f(ev[1]);
    out[g * 4 + 2] = softplus_f(ev[2]) + 1.0f;
    out[g * 4 + 3] = softplus_f(ev[3]);
}

// ===================== fallback (atomic path) =====================

template <bool FIRST>
__global__ __launch_bounds__(256) void edge_kernel_fb(
    const float* __restrict__ coords, const float* __restrict__ elen,
    const float* __restrict__ evec, const float* __restrict__ Wm,
    const float* __restrict__ bm, const int* __restrict__ nfrom,
    const int* __restrict__ nto, const float* __restrict__ state_prev,
    float* __restrict__ state_next, int E)
{
    int e = blockIdx.x * blockDim.x + threadIdx.x;
    if (e >= E) return;
    int nf = nfrom[e];
    int nt = nto[e];
    float cf0 = coords[nf*3+0], cf1 = coords[nf*3+1], cf2 = coords[nf*3+2];
    float ct0 = coords[nt*3+0], ct1 = coords[nt*3+1], ct2 = coords[nt*3+2];
    float ev0 = evec[e*3+0], ev1 = evec[e*3+1], ev2 = evec[e*3+2];
    float g0 = elen[e];
    float g1 = fabsf(cf0) + fabsf(cf1) + fabsf(cf2);
    float g2 = cf0*ct0 + cf1*ct1 + cf2*ct2;
    float g3 = cf0*ev0 + cf1*ev1 + cf2*ev2;
    float acc[SD];
#pragma unroll
    for (int j = 0; j < SD; j++) {
        acc[j] = bm[j] + g0*Wm[10*SD+j] + g1*Wm[11*SD+j] + g2*Wm[12*SD+j] + g3*Wm[13*SD+j];
    }
    if (!FIRST) {
        const float2* sp = (const float2*)(state_prev + (size_t)nf * SD);
        float s[SD];
#pragma unroll
        for (int h = 0; h < 5; h++) { float2 v = sp[h]; s[2*h] = v.x; s[2*h+1] = v.y; }
#pragma unroll
        for (int k = 0; k < SD; k++) {
#pragma unroll
            for (int j = 0; j < SD; j++) acc[j] += s[k] * Wm[k*SD+j];
        }
    }
    float* dst = state_next + (size_t)nt * SD;
#pragma unroll
    for (int j = 0; j < SD; j++) atomicAdd(dst + j, tanh_fast(acc[j]));
}

__global__ __launch_bounds__(256) void graph_reduce_fb(
    const float* __restrict__ state, const int* __restrict__ gidx,
    float* __restrict__ gstate, int N)
{
    int n = blockIdx.x * blockDim.x + threadIdx.x;
    if (n >= N) return;
    int g = gidx[n];
    const float2* sp = (const float2*)(state + (size_t)n * SD);
    float* dst = gstate + (size_t)g * SD;
#pragma unroll
    for (int h = 0; h < 5; h++) {
        float2 v = sp[h];
        atomicAdd(dst + 2*h, v.x);
        atomicAdd(dst + 2*h + 1, v.y);
    }
}

// ===================== launch =====================

extern "C" void kernel_launch(void* const* d_in, const int* in_sizes, int n_in,
                              void* d_out, int out_size, void* d_ws, size_t ws_size,
                              hipStream_t stream) {
    const float* coords = (const float*)d_in[0];
    const float* elen   = (const float*)d_in[1];
    const float* evec   = (const float*)d_in[2];
    const float* Wm     = (const float*)d_in[3];
    const float* bm     = (const float*)d_in[4];
    const float* Wo     = (const float*)d_in[5];
    const float* bo     = (const float*)d_in[6];
    const int* nfrom    = (const int*)d_in[7];
    const int* nto      = (const int*)d_in[8];
    const int* gidx     = (const int*)d_in[9];

    const int E = in_sizes[1];
    const int N = in_sizes[9];
    const int G = out_size / 4;

    const int NB = (N + BSZ - 1) / BSZ;      // buckets
    const size_t M = (size_t)NB * EB;        // per-(bucket,block) table size

    const int BLK = 256;
    const int ng = (N + BLK - 1) / BLK;
    const int gg = (G + BLK - 1) / BLK;

    auto align256 = [](size_t x) { return (x + 255) & ~(size_t)255; };
    const size_t state_bytes = align256((size_t)N * SD * sizeof(float));
    const size_t wst_bytes   = align256((size_t)N * SD * sizeof(__half) + 256);
    const size_t pay_bytes   = align256((size_t)E * sizeof(uvec4));
    const size_t gcnt_bytes  = align256(M * sizeof(unsigned));
    const size_t bsum_bytes  = align256((size_t)NB * sizeof(unsigned));
    const size_t bst_bytes   = align256((size_t)(NB + 1) * sizeof(unsigned));
    const size_t goff_bytes  = align256((size_t)(G + 1) * sizeof(unsigned));
    const size_t gst_bytes   = align256((size_t)G * SD * sizeof(float));
    const size_t c4_bytes    = align256((size_t)N * sizeof(float4));

    size_t o = 0;
    char* w = (char*)d_ws;
    float* stateA    = (float*)(w + o);    o += state_bytes;
    float* stateB    = (float*)(w + o);    o += state_bytes;
    __half* wsth     = (__half*)(w + o);   o += wst_bytes;
    uvec4* payA      = (uvec4*)(w + o);    o += pay_bytes;   // block-major
    uvec4* payB      = (uvec4*)(w + o);    o += pay_bytes;   // bucket-major sorted
    unsigned* gcnt   = (unsigned*)(w + o); o += gcnt_bytes;
    unsigned* eaddr  = (unsigned*)(w + o); o += gcnt_bytes;
    unsigned* bsum   = (unsigned*)(w + o); o += bsum_bytes;
    unsigned* bstart = (unsigned*)(w + o); o += bst_bytes;
    unsigned* goff   = (unsigned*)(w + o); o += goff_bytes;
    float* gstate    = (float*)(w + o);    o += gst_bytes;
    float4* coords4  = (float4*)(w + o);   o += c4_bytes;

    if (o <= ws_size && NB <= MAXNB && N < (1 << 18)) {
        // ---- prep + build (no global atomics) ----
        coords4_kernel<<<ng, BLK, 0, stream>>>(coords, coords4, N);
        bucket_count_kernel<<<EB, CTHR, 0, stream>>>(nto, gcnt, E, NB);
        bucket_scatter_kernel<<<EB, CTHR, 0, stream>>>(coords4, elen, evec, nfrom, nto,
                                                       gcnt, eaddr, payA, E, NB);
        rowsum_kernel<<<NB, 256, 0, stream>>>(gcnt, bsum);
        bscan_kernel<<<1, 256, 0, stream>>>(bsum, bstart, NB, E);
        sortperm_kernel<<<NB, CTHR, 0, stream>>>(gcnt, eaddr, bstart, payA, payB);
        // ---- rounds (contiguous, sorted, LLC-resident payload) ----
        round_run_kernel<true><<<NB, BLK, 0, stream>>>(bstart, payB, Wm, bm,
                                                       wsth, stateB, stateA, N, E);
        wstate_kernel<<<ng, BLK, 0, stream>>>(stateA, Wm, bm, wsth, N);
        round_run_kernel<false><<<NB, BLK, 0, stream>>>(bstart, payB, Wm, bm,
                                                        wsth, stateA, stateB, N, E);
        wstate_kernel<<<ng, BLK, 0, stream>>>(stateB, Wm, bm, wsth, N);
        round_run_kernel<false><<<NB, BLK, 0, stream>>>(bstart, payB, Wm, bm,
                                                        wsth, stateB, stateA, N, E);
        // ---- graph phase ----
        hipMemsetAsync(gstate, 0, (size_t)G * SD * sizeof(float), stream);
        goff_kernel<<<ng, BLK, 0, stream>>>(gidx, goff, N, G);
        gsum_kernel<<<(G * SD * 4 + BLK - 1) / BLK, BLK, 0, stream>>>(stateA, goff, gstate, G);
        out_kernel<<<gg, BLK, 0, stream>>>(gstate, Wo, bo, (float*)d_out, G);
    } else {
        // ---- fallback: atomic path ----
        const int eg = (E + BLK - 1) / BLK;
        float* gstateF = (float*)(w + 2 * state_bytes);
        hipMemsetAsync(stateA, 0, state_bytes, stream);
        hipMemsetAsync(gstateF, 0, (size_t)G * SD * sizeof(float), stream);
        edge_kernel_fb<true><<<eg, BLK, 0, stream>>>(coords, elen, evec, Wm, bm,
                                                     nfrom, nto, stateA, stateA, E);
        hipMemcpyAsync(stateB, stateA, state_bytes, hipMemcpyDeviceToDevice, stream);
        edge_kernel_fb<false><<<eg, BLK, 0, stream>>>(coords, elen, evec, Wm, bm,
                                                      nfrom, nto, stateA, stateB, E);
        hipMemcpyAsync(stateA, stateB, state_bytes, hipMemcpyDeviceToDevice, stream);
        edge_kernel_fb<false><<<eg, BLK, 0, stream>>>(coords, elen, evec, Wm, bm,
                                                      nfrom, nto, stateB, stateA, E);
        graph_reduce_fb<<<ng, BLK, 0, stream>>>(stateA, gidx, gstateF, N);
        out_kernel<<<gg, BLK, 0, stream>>>(gstateF, Wo, bo, (float*)d_out, G);
    }
}